// Round 1
// baseline (118.409 us; speedup 1.0000x reference)
//
#include <hip/hip_runtime.h>

#define PI_D 3.141592653589793
#define FS_D 16000.0
#define T_LEN 48000
#define L_CHUNK 128
#define N_CHUNKS 375
#define N_ROWS 124
#define SLOTS 1024          // 8 channels * 128 padded rows
#define ROWS_PER_BLK 64

// Constant block layout (float[64] in ws):
//  ch0 (lowpass):  [0]=b0 [1]=b1 [2]=b2 [3]=a1 [4]=a2
//  ch m>=1 (bp):   [ch*8+0]=b0 [ch*8+1]=cr [ch*8+2]=ci [ch*8+3]=keep_phase

__device__ __forceinline__ double mfc_of(int m) {
    // replicate reference double arithmetic exactly (sequential f *= r)
    if (m == 0) return 5.0;
    if (m == 1) return 10.0;
    double r = (1.0 + 1.0 / (2.0 * 2.0)) / (1.0 - 1.0 / (2.0 * 2.0));
    double f = 10.0 * r;
    for (int i = 2; i < m; ++i) f *= r;
    return f;
}

__global__ void mfb_setup(float* __restrict__ cst) {
    int ch = threadIdx.x;
    if (ch >= 8) return;
    if (ch == 0) {
        double K   = tan(PI_D * 2.5 / FS_D);
        double nrm = 1.0 / (1.0 + sqrt(2.0) * K + K * K);
        cst[0] = (float)(K * K * nrm);
        cst[1] = (float)(2.0 * K * K * nrm);
        cst[2] = (float)(K * K * nrm);
        cst[3] = (float)(2.0 * (K * K - 1.0) * nrm);
        cst[4] = (float)((1.0 - sqrt(2.0) * K + K * K) * nrm);
    } else {
        int m = ch - 1;
        double mfc = mfc_of(m);
        double bw  = (mfc <= 10.0) ? 5.0 : mfc / 2.0;
        double e0  = exp(-PI_D * bw / FS_D);
        double th  = 2.0 * PI_D * mfc / FS_D;
        cst[ch * 8 + 0] = (float)(1.0 - e0);
        cst[ch * 8 + 1] = (float)(e0 * cos(th));
        cst[ch * 8 + 2] = (float)(e0 * sin(th));
        cst[ch * 8 + 3] = (m < 2) ? 1.0f : 0.0f;
    }
}

// Phase 1 (FINAL=false): zero-init chunk scan, write final state only.
// Phase 3 (FINAL=true):  scan from corrected init state, write outputs.
template <bool FINAL>
__global__ __launch_bounds__(512) void mfb_chunk(const float* __restrict__ x,
                                                 const float* __restrict__ cst,
                                                 float2* __restrict__ ws_fin,
                                                 const float2* __restrict__ ws_init,
                                                 float* __restrict__ out) {
    __shared__ float xs[ROWS_PER_BLK][L_CHUNK + 1];  // +1 pad: column reads 2-way/bank (free)
    const int t     = threadIdx.x;                   // 0..511
    const int j     = blockIdx.y;                    // chunk index
    const int n0    = (int)blockIdx.x * ROWS_PER_BLK;
    const int tbase = j * L_CHUNK;

    // ---- stage x tile [64 rows][128 samples] into LDS, coalesced float4 ----
#pragma unroll
    for (int i = 0; i < 4; ++i) {
        int flat = (i * 512 + t) * 4;   // 0..8188
        int r = flat >> 7, c = flat & 127;
        int n = n0 + r;
        float4 v = make_float4(0.f, 0.f, 0.f, 0.f);
        if (n < N_ROWS)
            v = *reinterpret_cast<const float4*>(x + (size_t)n * T_LEN + tbase + c);
        xs[r][c + 0] = v.x; xs[r][c + 1] = v.y; xs[r][c + 2] = v.z; xs[r][c + 3] = v.w;
    }
    __syncthreads();

    const int ch   = t >> 6;        // wave-uniform channel
    const int nn   = t & 63;
    const int n    = n0 + nn;
    const int slot = ch * 128 + n;
    const int widx = j * SLOTS + slot;

    if (ch == 0) {
        // ---- 2nd-order Butterworth lowpass, DF2T ----
        const float b0 = cst[0], b1 = cst[1], b2 = cst[2], a1 = cst[3], a2 = cst[4];
        float s0 = 0.f, s1 = 0.f;
        if (FINAL) { float2 u = ws_init[widx]; s0 = u.x; s1 = u.y; }
        float* orow = FINAL ? (out + (size_t)(n * 8) * T_LEN + tbase) : nullptr;
        for (int b = 0; b < L_CHUNK / 16; ++b) {
            float buf[16];
#pragma unroll
            for (int k = 0; k < 16; ++k) {
                float xv = xs[nn][b * 16 + k];
                float y  = fmaf(b0, xv, s0);
                s0 = fmaf(b1, xv, fmaf(-a1, y, s1));
                s1 = fmaf(b2, xv, -a2 * y);
                if (FINAL) buf[k] = 2.0f * y;
            }
            if (FINAL && n < N_ROWS) {
                float4* p = reinterpret_cast<float4*>(orow + b * 16);
                p[0] = make_float4(buf[0], buf[1], buf[2], buf[3]);
                p[1] = make_float4(buf[4], buf[5], buf[6], buf[7]);
                p[2] = make_float4(buf[8], buf[9], buf[10], buf[11]);
                p[3] = make_float4(buf[12], buf[13], buf[14], buf[15]);
            }
        }
        if (!FINAL) ws_fin[widx] = make_float2(s0, s1);
    } else {
        // ---- complex first-order resonator ----
        const float b0 = cst[ch * 8 + 0], cr = cst[ch * 8 + 1], ci = cst[ch * 8 + 2];
        const bool  kp = cst[ch * 8 + 3] != 0.0f;
        float yr = 0.f, yi = 0.f;
        if (FINAL) { float2 u = ws_init[widx]; yr = u.x; yi = u.y; }
        float* orow = FINAL ? (out + (size_t)(n * 8 + ch) * T_LEN + tbase) : nullptr;
        for (int b = 0; b < L_CHUNK / 16; ++b) {
            float buf[16];
#pragma unroll
            for (int k = 0; k < 16; ++k) {
                float xv  = xs[nn][b * 16 + k];
                float nyr = fmaf(cr, yr, fmaf(-ci, yi, b0 * xv));
                float nyi = fmaf(cr, yi, ci * yr);
                yr = nyr; yi = nyi;
                if (FINAL)
                    buf[k] = kp ? 2.0f * yr : 2.0f * sqrtf(fmaf(yr, yr, yi * yi));
            }
            if (FINAL && n < N_ROWS) {
                float4* p = reinterpret_cast<float4*>(orow + b * 16);
                p[0] = make_float4(buf[0], buf[1], buf[2], buf[3]);
                p[1] = make_float4(buf[4], buf[5], buf[6], buf[7]);
                p[2] = make_float4(buf[8], buf[9], buf[10], buf[11]);
                p[3] = make_float4(buf[12], buf[13], buf[14], buf[15]);
            }
        }
        if (!FINAL) ws_fin[widx] = make_float2(yr, yi);
    }
}

// Phase 2: sequential recomposition of chunk-boundary states (double precision).
// u[0] = 0 ; u[j] = F0[j-1] + P * u[j-1]   (P = homogeneous propagator over L samples)
__global__ void mfb_combine(const float2* __restrict__ ws_fin, float2* __restrict__ ws_init) {
    int s = blockIdx.x * 256 + threadIdx.x;
    if (s >= SLOTS) return;
    int ch = s >> 7;
    if (ch == 0) {
        double K   = tan(PI_D * 2.5 / FS_D);
        double nrm = 1.0 / (1.0 + sqrt(2.0) * K + K * K);
        double a1  = 2.0 * (K * K - 1.0) * nrm;
        double a2  = (1.0 - sqrt(2.0) * K + K * K) * nrm;
        // A = [[-a1, 1], [-a2, 0]]; P = A^128 by 7 squarings
        double p00 = -a1, p01 = 1.0, p10 = -a2, p11 = 0.0;
        for (int i = 0; i < 7; ++i) {
            double q00 = p00 * p00 + p01 * p10, q01 = p00 * p01 + p01 * p11;
            double q10 = p10 * p00 + p11 * p10, q11 = p10 * p01 + p11 * p11;
            p00 = q00; p01 = q01; p10 = q10; p11 = q11;
        }
        double u0 = 0.0, u1 = 0.0;
        for (int j = 0; j < N_CHUNKS; ++j) {
            ws_init[j * SLOTS + s] = make_float2((float)u0, (float)u1);
            float2 f = ws_fin[j * SLOTS + s];
            double t0 = (double)f.x + p00 * u0 + p01 * u1;
            double t1 = (double)f.y + p10 * u0 + p11 * u1;
            u0 = t0; u1 = t1;
        }
    } else {
        int m = ch - 1;
        double mfc = mfc_of(m);
        double bw  = (mfc <= 10.0) ? 5.0 : mfc * 0.5;
        double th  = 2.0 * PI_D * mfc / FS_D;
        double eL  = exp(-PI_D * bw * (double)L_CHUNK / FS_D);  // e0^L
        double ang = th * (double)L_CHUNK;
        double Pr = eL * cos(ang), Pi = eL * sin(ang);
        double ur = 0.0, ui = 0.0;
        for (int j = 0; j < N_CHUNKS; ++j) {
            ws_init[j * SLOTS + s] = make_float2((float)ur, (float)ui);
            float2 f = ws_fin[j * SLOTS + s];
            double tr = (double)f.x + Pr * ur - Pi * ui;
            double ti = (double)f.y + Pr * ui + Pi * ur;
            ur = tr; ui = ti;
        }
    }
}

extern "C" void kernel_launch(void* const* d_in, const int* in_sizes, int n_in,
                              void* d_out, int out_size, void* d_ws, size_t ws_size,
                              hipStream_t stream) {
    const float* x = (const float*)d_in[0];
    float* out = (float*)d_out;
    char* ws = (char*)d_ws;
    float*  cst     = (float*)ws;                        // 256 B
    float2* ws_fin  = (float2*)(ws + 256);               // 375*1024*8 = 3,072,000 B
    float2* ws_init = (float2*)(ws + 256 + 3072000);     // same size

    mfb_setup<<<1, 64, 0, stream>>>(cst);
    dim3 grid(2, N_CHUNKS);
    mfb_chunk<false><<<grid, 512, 0, stream>>>(x, cst, ws_fin, nullptr, nullptr);
    mfb_combine<<<4, 256, 0, stream>>>(ws_fin, ws_init);
    mfb_chunk<true><<<grid, 512, 0, stream>>>(x, cst, nullptr, ws_init, out);
}

// Round 2
// 102.972 us; speedup vs baseline: 1.1499x; 1.1499x over previous
//
#include <hip/hip_runtime.h>
#include <cmath>

#define T_LEN 48000
#define L_CHUNK 128
#define N_CHUNKS 375
#define N_ROWS 124
#define SLOTS 1024          // 8 channels * 128 padded rows
#define ROWS_PER_BLK 64
#define CBATCH 25
#define NBATCH 15           // CBATCH * NBATCH == N_CHUNKS

struct CoefF {
    float lp_b0, lp_b1, lp_b2, lp_a1, lp_a2;
    float bp_b0[7], bp_cr[7], bp_ci[7];
};
struct CoefD {
    double p00, p01, p10, p11;   // LP homogeneous propagator A^L
    double Pr[7], Pi[7];         // resonator propagators c^L
};

// Phase 1 (FINAL=false): zero-init chunk scan, write final state only.
// Phase 3 (FINAL=true):  scan from corrected init state, write outputs.
template <bool FINAL>
__global__ __launch_bounds__(512) void mfb_chunk(const float* __restrict__ x,
                                                 CoefF C,
                                                 float2* __restrict__ ws_fin,
                                                 const float2* __restrict__ ws_init,
                                                 float* __restrict__ out) {
    __shared__ float xs[ROWS_PER_BLK][L_CHUNK + 1];  // +1 pad: column reads 2-way/bank (free)
    const int t     = threadIdx.x;                   // 0..511
    const int j     = blockIdx.y;                    // chunk index
    const int n0    = (int)blockIdx.x * ROWS_PER_BLK;
    const int tbase = j * L_CHUNK;

    // ---- stage x tile [64 rows][128 samples] into LDS, coalesced float4 ----
#pragma unroll
    for (int i = 0; i < 4; ++i) {
        int flat = (i * 512 + t) * 4;   // 0..8188
        int r = flat >> 7, c = flat & 127;
        int n = n0 + r;
        float4 v = make_float4(0.f, 0.f, 0.f, 0.f);
        if (n < N_ROWS)
            v = *reinterpret_cast<const float4*>(x + (size_t)n * T_LEN + tbase + c);
        xs[r][c + 0] = v.x; xs[r][c + 1] = v.y; xs[r][c + 2] = v.z; xs[r][c + 3] = v.w;
    }
    __syncthreads();

    const int ch   = t >> 6;        // wave-uniform channel
    const int nn   = t & 63;
    const int n    = n0 + nn;
    const int slot = ch * 128 + n;
    const int widx = j * SLOTS + slot;

    if (ch == 0) {
        // ---- 2nd-order Butterworth lowpass, DF2T ----
        const float b0 = C.lp_b0, b1 = C.lp_b1, b2 = C.lp_b2, a1 = C.lp_a1, a2 = C.lp_a2;
        float s0 = 0.f, s1 = 0.f;
        if (FINAL) { float2 u = ws_init[widx]; s0 = u.x; s1 = u.y; }
        float* orow = FINAL ? (out + (size_t)(n * 8) * T_LEN + tbase) : nullptr;
        for (int b = 0; b < L_CHUNK / 16; ++b) {
            float buf[16];
#pragma unroll
            for (int k = 0; k < 16; ++k) {
                float xv = xs[nn][b * 16 + k];
                float y  = fmaf(b0, xv, s0);
                s0 = fmaf(b1, xv, fmaf(-a1, y, s1));
                s1 = fmaf(b2, xv, -a2 * y);
                if (FINAL) buf[k] = 2.0f * y;
            }
            if (FINAL && n < N_ROWS) {
                float4* p = reinterpret_cast<float4*>(orow + b * 16);
                p[0] = make_float4(buf[0], buf[1], buf[2], buf[3]);
                p[1] = make_float4(buf[4], buf[5], buf[6], buf[7]);
                p[2] = make_float4(buf[8], buf[9], buf[10], buf[11]);
                p[3] = make_float4(buf[12], buf[13], buf[14], buf[15]);
            }
        }
        if (!FINAL) ws_fin[widx] = make_float2(s0, s1);
    } else {
        // ---- complex first-order resonator ----
        float b0 = 0.f, cr = 0.f, ci = 0.f;
#pragma unroll
        for (int c = 1; c < 8; ++c)
            if (ch == c) { b0 = C.bp_b0[c - 1]; cr = C.bp_cr[c - 1]; ci = C.bp_ci[c - 1]; }
        const bool kp = (ch <= 2);   // mfc = 5, 10 Hz keep phase
        float yr = 0.f, yi = 0.f;
        if (FINAL) { float2 u = ws_init[widx]; yr = u.x; yi = u.y; }
        float* orow = FINAL ? (out + (size_t)(n * 8 + ch) * T_LEN + tbase) : nullptr;
        for (int b = 0; b < L_CHUNK / 16; ++b) {
            float buf[16];
#pragma unroll
            for (int k = 0; k < 16; ++k) {
                float xv  = xs[nn][b * 16 + k];
                float nyr = fmaf(cr, yr, fmaf(-ci, yi, b0 * xv));
                float nyi = fmaf(cr, yi, ci * yr);
                yr = nyr; yi = nyi;
                if (FINAL)
                    buf[k] = kp ? 2.0f * yr : 2.0f * sqrtf(fmaf(yr, yr, yi * yi));
            }
            if (FINAL && n < N_ROWS) {
                float4* p = reinterpret_cast<float4*>(orow + b * 16);
                p[0] = make_float4(buf[0], buf[1], buf[2], buf[3]);
                p[1] = make_float4(buf[4], buf[5], buf[6], buf[7]);
                p[2] = make_float4(buf[8], buf[9], buf[10], buf[11]);
                p[3] = make_float4(buf[12], buf[13], buf[14], buf[15]);
            }
        }
        if (!FINAL) ws_fin[widx] = make_float2(yr, yi);
    }
}

// Phase 2: sequential recomposition of chunk-boundary states (double precision),
// software-pipelined: load batch b+1 into registers while processing batch b.
// u[0] = 0 ; u[j+1] = F0[j] + P * u[j]
__global__ __launch_bounds__(256) void mfb_combine(const float2* __restrict__ ws_fin,
                                                   float2* __restrict__ ws_init,
                                                   CoefD D) {
    int s = blockIdx.x * 256 + threadIdx.x;
    if (s >= SLOTS) return;
    int ch = s >> 7;

    double m00, m01, m10, m11;   // propagator as real 2x2 on (u0,u1)
    if (ch == 0) {
        m00 = D.p00; m01 = D.p01; m10 = D.p10; m11 = D.p11;
    } else {
        double Pr = 0.0, Pi = 0.0;
#pragma unroll
        for (int c = 1; c < 8; ++c) if (ch == c) { Pr = D.Pr[c - 1]; Pi = D.Pi[c - 1]; }
        m00 = Pr; m01 = -Pi; m10 = Pi; m11 = Pr;
    }

    double u0 = 0.0, u1 = 0.0;
    const float2* base = ws_fin + s;
    float2 fa[CBATCH], fb[CBATCH];

    auto LOAD = [&](float2 (&f)[CBATCH], int jbase) {
#pragma unroll
        for (int i = 0; i < CBATCH; ++i) f[i] = base[(size_t)(jbase + i) * SLOTS];
    };
    auto PROC = [&](const float2 (&f)[CBATCH], int jbase) {
#pragma unroll
        for (int i = 0; i < CBATCH; ++i) {
            ws_init[(size_t)(jbase + i) * SLOTS + s] = make_float2((float)u0, (float)u1);
            double t0 = (double)f[i].x + m00 * u0 + m01 * u1;
            double t1 = (double)f[i].y + m10 * u0 + m11 * u1;
            u0 = t0; u1 = t1;
        }
    };

    LOAD(fa, 0);
    for (int bt = 0; bt < NBATCH; bt += 2) {
        if (bt + 1 < NBATCH) LOAD(fb, (bt + 1) * CBATCH);
        PROC(fa, bt * CBATCH);
        if (bt + 2 < NBATCH) LOAD(fa, (bt + 2) * CBATCH);
        if (bt + 1 < NBATCH) PROC(fb, (bt + 1) * CBATCH);
    }
}

extern "C" void kernel_launch(void* const* d_in, const int* in_sizes, int n_in,
                              void* d_out, int out_size, void* d_ws, size_t ws_size,
                              hipStream_t stream) {
    const float* x = (const float*)d_in[0];
    float* out = (float*)d_out;
    char* ws = (char*)d_ws;
    float2* ws_fin  = (float2*)ws;                 // 375*1024*8 = 3,072,000 B
    float2* ws_init = (float2*)(ws + 3072000);     // same size

    // ---- host-side coefficient computation (double, cast to f32 like the ref) ----
    const double PI = 3.141592653589793;
    const double FS = 16000.0;
    CoefF C; CoefD D;
    {
        double K   = tan(PI * 2.5 / FS);
        double nrm = 1.0 / (1.0 + sqrt(2.0) * K + K * K);
        double a1  = 2.0 * (K * K - 1.0) * nrm;
        double a2  = (1.0 - sqrt(2.0) * K + K * K) * nrm;
        C.lp_b0 = (float)(K * K * nrm);
        C.lp_b1 = (float)(2.0 * K * K * nrm);
        C.lp_b2 = (float)(K * K * nrm);
        C.lp_a1 = (float)a1;
        C.lp_a2 = (float)a2;
        // A = [[-a1,1],[-a2,0]]; P = A^128 by 7 squarings
        double p00 = -a1, p01 = 1.0, p10 = -a2, p11 = 0.0;
        for (int i = 0; i < 7; ++i) {
            double q00 = p00 * p00 + p01 * p10, q01 = p00 * p01 + p01 * p11;
            double q10 = p10 * p00 + p11 * p10, q11 = p10 * p01 + p11 * p11;
            p00 = q00; p01 = q01; p10 = q10; p11 = q11;
        }
        D.p00 = p00; D.p01 = p01; D.p10 = p10; D.p11 = p11;

        // mfc list: 5, 10, then 10*r^k (r = 5/3) up to 150  -> 7 bandpass channels
        double r = (1.0 + 1.0 / 4.0) / (1.0 - 1.0 / 4.0);
        double mfc[7]; mfc[0] = 5.0; mfc[1] = 10.0;
        double f = 10.0 * r;
        for (int m = 2; m < 7; ++m) { mfc[m] = f; f *= r; }
        for (int m = 0; m < 7; ++m) {
            double bw = (mfc[m] <= 10.0) ? 5.0 : mfc[m] * 0.5;
            double e0 = exp(-PI * bw / FS);
            double th = 2.0 * PI * mfc[m] / FS;
            C.bp_b0[m] = (float)(1.0 - e0);
            C.bp_cr[m] = (float)(e0 * cos(th));
            C.bp_ci[m] = (float)(e0 * sin(th));
            double eL  = exp(-PI * bw * (double)L_CHUNK / FS);
            double ang = th * (double)L_CHUNK;
            D.Pr[m] = eL * cos(ang);
            D.Pi[m] = eL * sin(ang);
        }
    }

    dim3 grid(2, N_CHUNKS);
    mfb_chunk<false><<<grid, 512, 0, stream>>>(x, C, ws_fin, nullptr, nullptr);
    mfb_combine<<<4, 256, 0, stream>>>(ws_fin, ws_init, D);
    mfb_chunk<true><<<grid, 512, 0, stream>>>(x, C, nullptr, ws_init, out);
}

// Round 3
// 85.069 us; speedup vs baseline: 1.3919x; 1.2104x over previous
//
#include <hip/hip_runtime.h>
#include <cmath>

#define T_LEN 48000
#define L_CHUNK 128
#define N_CHUNKS 375
#define N_ROWS 124
#define SLOTS 1024          // 8 channels * 128 padded rows
#define ROWS_PER_BLK 64
#define XS_STRIDE 132       // 128 + 4 pad: 528 B rows, 16B-aligned, float4-clean
#define TR_STRIDE 20        // 16 + 4 pad: 80 B rows, 16B-aligned
#define CBATCH 25
#define NBATCH 15           // CBATCH * NBATCH == N_CHUNKS

struct CoefF {
    float lp_b0, lp_b1, lp_b2, lp_a1, lp_a2;
    float bp_b0[7], bp_cr[7], bp_ci[7];
};
struct CoefD {
    double p00, p01, p10, p11;   // LP homogeneous propagator A^L
    double Pr[7], Pi[7];         // resonator propagators c^L
};

// Phase 1 (FINAL=false): zero-init chunk scan, write final state only.
// Phase 3 (FINAL=true):  scan from corrected init state, write outputs
//                        (coalesced via per-wave LDS transpose tile).
template <bool FINAL>
__global__ __launch_bounds__(512) void mfb_chunk(const float* __restrict__ x,
                                                 CoefF C,
                                                 float2* __restrict__ ws_fin,
                                                 const float2* __restrict__ ws_init,
                                                 float* __restrict__ out) {
    extern __shared__ __align__(16) float smem[];
    float* xs = smem;                                  // [64][XS_STRIDE]
    const int t     = threadIdx.x;                     // 0..511
    const int j     = blockIdx.y;                      // chunk index
    const int n0    = (int)blockIdx.x * ROWS_PER_BLK;
    const int tbase = j * L_CHUNK;

    // ---- stage x tile [64 rows][128 samples] into LDS, float4 both sides ----
#pragma unroll
    for (int i = 0; i < 4; ++i) {
        int g = i * 512 + t;            // float4-granule 0..2047
        int r = g >> 5, c = (g & 31) * 4;
        int n = n0 + r;
        float4 v = make_float4(0.f, 0.f, 0.f, 0.f);
        if (n < N_ROWS)
            v = *reinterpret_cast<const float4*>(x + (size_t)n * T_LEN + tbase + c);
        *reinterpret_cast<float4*>(xs + r * XS_STRIDE + c) = v;
    }
    __syncthreads();

    const int ch   = t >> 6;        // wave-uniform channel
    const int nn   = t & 63;        // lane = stream within block
    const int n    = n0 + nn;
    const int slot = ch * 128 + n;
    const int widx = j * SLOTS + slot;
    float* trw = FINAL ? (smem + ROWS_PER_BLK * XS_STRIDE + ch * (64 * TR_STRIDE)) : nullptr;

    // filter coefficients (wave-uniform selection, static indices)
    float f_b0, f_b1 = 0.f, f_b2 = 0.f, f_a1 = 0.f, f_a2 = 0.f, f_cr = 0.f, f_ci = 0.f;
    if (ch == 0) {
        f_b0 = C.lp_b0; f_b1 = C.lp_b1; f_b2 = C.lp_b2; f_a1 = C.lp_a1; f_a2 = C.lp_a2;
    } else {
        f_b0 = 0.f;
#pragma unroll
        for (int c = 1; c < 8; ++c)
            if (ch == c) { f_b0 = C.bp_b0[c - 1]; f_cr = C.bp_cr[c - 1]; f_ci = C.bp_ci[c - 1]; }
    }
    const bool kp = (ch <= 2);      // ch0 lowpass / mfc=5,10 keep phase (real path)

    float s0 = 0.f, s1 = 0.f;       // LP state or resonator (yr, yi)
    if (FINAL) { float2 u = ws_init[widx]; s0 = u.x; s1 = u.y; }

    for (int b = 0; b < L_CHUNK / 16; ++b) {
        float4 xv4[4];
#pragma unroll
        for (int q = 0; q < 4; ++q)
            xv4[q] = *reinterpret_cast<const float4*>(xs + nn * XS_STRIDE + b * 16 + q * 4);
        const float* xv = reinterpret_cast<const float*>(xv4);

        float buf[16];
        if (ch == 0) {
#pragma unroll
            for (int k = 0; k < 16; ++k) {
                float xvk = xv[k];
                float y  = fmaf(f_b0, xvk, s0);
                s0 = fmaf(f_b1, xvk, fmaf(-f_a1, y, s1));
                s1 = fmaf(f_b2, xvk, -f_a2 * y);
                if (FINAL) buf[k] = 2.0f * y;
            }
        } else {
#pragma unroll
            for (int k = 0; k < 16; ++k) {
                float xvk = xv[k];
                float nyr = fmaf(f_cr, s0, fmaf(-f_ci, s1, f_b0 * xvk));
                float nyi = fmaf(f_cr, s1, f_ci * s0);
                s0 = nyr; s1 = nyi;
                if (FINAL)
                    buf[k] = kp ? 2.0f * nyr : 2.0f * sqrtf(fmaf(nyr, nyr, nyi * nyi));
            }
        }

        if (FINAL) {
            // ---- per-wave transpose: tile rows = streams, cols = 16 samples ----
            asm volatile("s_waitcnt lgkmcnt(0)" ::: "memory");  // prev granule's reads done
            *reinterpret_cast<float4*>(trw + nn * TR_STRIDE + 0)  = make_float4(buf[0], buf[1], buf[2], buf[3]);
            *reinterpret_cast<float4*>(trw + nn * TR_STRIDE + 4)  = make_float4(buf[4], buf[5], buf[6], buf[7]);
            *reinterpret_cast<float4*>(trw + nn * TR_STRIDE + 8)  = make_float4(buf[8], buf[9], buf[10], buf[11]);
            *reinterpret_cast<float4*>(trw + nn * TR_STRIDE + 12) = make_float4(buf[12], buf[13], buf[14], buf[15]);
            asm volatile("s_waitcnt lgkmcnt(0)" ::: "memory");  // tile visible to whole wave
#pragma unroll
            for (int s = 0; s < 4; ++s) {
                int rr = s * 16 + (nn >> 2);       // tile row (stream) this lane stores
                int kk = (nn & 3) * 4;             // sample offset within granule
                int nrow = n0 + rr;
                if (nrow < N_ROWS) {
                    float4 v = *reinterpret_cast<const float4*>(trw + rr * TR_STRIDE + kk);
                    *reinterpret_cast<float4*>(out + (size_t)(nrow * 8 + ch) * T_LEN
                                               + tbase + b * 16 + kk) = v;
                }
            }
        }
    }
    if (!FINAL) ws_fin[widx] = make_float2(s0, s1);
}

// Phase 2: sequential recomposition of chunk-boundary states (double precision),
// software-pipelined: load batch b+1 into registers while processing batch b.
__global__ __launch_bounds__(256) void mfb_combine(const float2* __restrict__ ws_fin,
                                                   float2* __restrict__ ws_init,
                                                   CoefD D) {
    int s = blockIdx.x * 256 + threadIdx.x;
    if (s >= SLOTS) return;
    int ch = s >> 7;

    double m00, m01, m10, m11;   // propagator as real 2x2 on (u0,u1)
    if (ch == 0) {
        m00 = D.p00; m01 = D.p01; m10 = D.p10; m11 = D.p11;
    } else {
        double Pr = 0.0, Pi = 0.0;
#pragma unroll
        for (int c = 1; c < 8; ++c) if (ch == c) { Pr = D.Pr[c - 1]; Pi = D.Pi[c - 1]; }
        m00 = Pr; m01 = -Pi; m10 = Pi; m11 = Pr;
    }

    double u0 = 0.0, u1 = 0.0;
    const float2* base = ws_fin + s;
    float2 fa[CBATCH], fb[CBATCH];

    auto LOAD = [&](float2 (&f)[CBATCH], int jbase) {
#pragma unroll
        for (int i = 0; i < CBATCH; ++i) f[i] = base[(size_t)(jbase + i) * SLOTS];
    };
    auto PROC = [&](const float2 (&f)[CBATCH], int jbase) {
#pragma unroll
        for (int i = 0; i < CBATCH; ++i) {
            ws_init[(size_t)(jbase + i) * SLOTS + s] = make_float2((float)u0, (float)u1);
            double t0 = (double)f[i].x + m00 * u0 + m01 * u1;
            double t1 = (double)f[i].y + m10 * u0 + m11 * u1;
            u0 = t0; u1 = t1;
        }
    };

    LOAD(fa, 0);
    for (int bt = 0; bt < NBATCH; bt += 2) {
        if (bt + 1 < NBATCH) LOAD(fb, (bt + 1) * CBATCH);
        PROC(fa, bt * CBATCH);
        if (bt + 2 < NBATCH) LOAD(fa, (bt + 2) * CBATCH);
        if (bt + 1 < NBATCH) PROC(fb, (bt + 1) * CBATCH);
    }
}

extern "C" void kernel_launch(void* const* d_in, const int* in_sizes, int n_in,
                              void* d_out, int out_size, void* d_ws, size_t ws_size,
                              hipStream_t stream) {
    const float* x = (const float*)d_in[0];
    float* out = (float*)d_out;
    char* ws = (char*)d_ws;
    float2* ws_fin  = (float2*)ws;                 // 375*1024*8 = 3,072,000 B
    float2* ws_init = (float2*)(ws + 3072000);     // same size

    // ---- host-side coefficient computation (double, cast to f32 like the ref) ----
    const double PI = 3.141592653589793;
    const double FS = 16000.0;
    CoefF C; CoefD D;
    {
        double K   = tan(PI * 2.5 / FS);
        double nrm = 1.0 / (1.0 + sqrt(2.0) * K + K * K);
        double a1  = 2.0 * (K * K - 1.0) * nrm;
        double a2  = (1.0 - sqrt(2.0) * K + K * K) * nrm;
        C.lp_b0 = (float)(K * K * nrm);
        C.lp_b1 = (float)(2.0 * K * K * nrm);
        C.lp_b2 = (float)(K * K * nrm);
        C.lp_a1 = (float)a1;
        C.lp_a2 = (float)a2;
        // A = [[-a1,1],[-a2,0]]; P = A^128 by 7 squarings
        double p00 = -a1, p01 = 1.0, p10 = -a2, p11 = 0.0;
        for (int i = 0; i < 7; ++i) {
            double q00 = p00 * p00 + p01 * p10, q01 = p00 * p01 + p01 * p11;
            double q10 = p10 * p00 + p11 * p10, q11 = p10 * p01 + p11 * p11;
            p00 = q00; p01 = q01; p10 = q10; p11 = q11;
        }
        D.p00 = p00; D.p01 = p01; D.p10 = p10; D.p11 = p11;

        // mfc list: 5, 10, then 10*r^k (r = 5/3) up to 150  -> 7 bandpass channels
        double r = (1.0 + 1.0 / 4.0) / (1.0 - 1.0 / 4.0);
        double mfc[7]; mfc[0] = 5.0; mfc[1] = 10.0;
        double f = 10.0 * r;
        for (int m = 2; m < 7; ++m) { mfc[m] = f; f *= r; }
        for (int m = 0; m < 7; ++m) {
            double bw = (mfc[m] <= 10.0) ? 5.0 : mfc[m] * 0.5;
            double e0 = exp(-PI * bw / FS);
            double th = 2.0 * PI * mfc[m] / FS;
            C.bp_b0[m] = (float)(1.0 - e0);
            C.bp_cr[m] = (float)(e0 * cos(th));
            C.bp_ci[m] = (float)(e0 * sin(th));
            double eL  = exp(-PI * bw * (double)L_CHUNK / FS);
            double ang = th * (double)L_CHUNK;
            D.Pr[m] = eL * cos(ang);
            D.Pi[m] = eL * sin(ang);
        }
    }

    const int smem1 = ROWS_PER_BLK * XS_STRIDE * 4;                    // 33792 B
    const int smem3 = smem1 + 8 * 64 * TR_STRIDE * 4;                  // 74752 B
    dim3 grid(2, N_CHUNKS);
    mfb_chunk<false><<<grid, 512, smem1, stream>>>(x, C, ws_fin, nullptr, nullptr);
    mfb_combine<<<4, 256, 0, stream>>>(ws_fin, ws_init, D);
    mfb_chunk<true><<<grid, 512, smem3, stream>>>(x, C, nullptr, ws_init, out);
}